// Round 2
// baseline (1913.419 us; speedup 1.0000x reference)
//
#include <hip/hip_runtime.h>
#include <hip/hip_bf16.h>
#include <stdint.h>

// Problem constants (PrismEncoder)
#define B_   128
#define N1_  256
#define N2_  256
#define D_   256
#define H_   8
#define DH_  32
#define DFF_ 1024
#define M_   (B_*N1_)   // 32768 rows

typedef unsigned short ushortT;
typedef unsigned int   uintT;

__device__ __forceinline__ float b2f(ushortT u){ return __uint_as_float(((uintT)u)<<16); }
__device__ __forceinline__ ushortT f2b(float f){
  uintT u = __float_as_uint(f);
  uintT r = (u + 0x7fffu + ((u>>16)&1u)) >> 16;   // RNE
  return (ushortT)r;
}

// Dtype sniff: look at 64 ushorts of x1 (~N(0,1)). If bf16, exponent fields are
// in [100,135] (values ~[1e-8, 512]); if the buffer is really f32, half the
// ushorts are float mantissa halves with ~uniform "exponent" -> ~43% bad.
__device__ __forceinline__ int sniff_is_f32(const ushortT* x){
  int bad = 0;
  #pragma unroll
  for (int i = 0; i < 64; i++) {
    int e = (x[i] >> 7) & 0xff;
    bad += (e < 100 || e > 135) ? 1 : 0;
  }
  return bad >= 12;
}

// Load one element from an INPUT tensor (dtype per flag).
__device__ __forceinline__ float ldin(const void* p, size_t i, int f32){
  return f32 ? ((const float*)p)[i] : b2f(((const ushortT*)p)[i]);
}

// ---------------------------------------------------------------------------
// GEMM: out[M,N](bf16) = A[M,K] @ W[K,N] + bias[N], optional relu.
// A dtype: bf16 if a_dyn==0 (intermediate), else sniffed input dtype.
// W/bias: sniffed input dtype. Accumulate fp32, output always bf16.
// ---------------------------------------------------------------------------
__global__ __launch_bounds__(256) void gemm_bias_kernel(
    const void* __restrict__ A, const void* __restrict__ W,
    const void* __restrict__ bias, ushortT* __restrict__ out,
    int M, int N, int K, int relu, const ushortT* __restrict__ sniffp, int a_dyn)
{
  __shared__ float As[16][68];  // [k][m], padded
  __shared__ float Bs[16][68];  // [k][n], padded
  const int tid = threadIdx.x;
  const int in_f32 = sniff_is_f32(sniffp);
  const int af32 = a_dyn ? in_f32 : 0;

  const int tx = tid & 15, ty = tid >> 4;
  const int row0 = blockIdx.x * 64, col0 = blockIdx.y * 64;
  const int m0 = ty * 4, n0 = tx * 4;

  float acc[4][4];
  #pragma unroll
  for (int i = 0; i < 4; i++)
    #pragma unroll
    for (int j = 0; j < 4; j++) acc[i][j] = 0.f;

  const int lm = tid >> 2;         // 0..63  (A row within tile)
  const int lk = (tid & 3) * 4;    // 0,4,8,12
  const int bk = tid >> 4;         // 0..15  (W row within tile)
  const int bn = (tid & 15) * 4;   // 0..60

  for (int kt = 0; kt < K; kt += 16) {
    const size_t ai = (size_t)(row0 + lm) * K + kt + lk;
    if (af32) {
      float4 av = *(const float4*)((const float*)A + ai);
      As[lk + 0][lm] = av.x; As[lk + 1][lm] = av.y;
      As[lk + 2][lm] = av.z; As[lk + 3][lm] = av.w;
    } else {
      ushort4 av = *(const ushort4*)((const ushortT*)A + ai);
      As[lk + 0][lm] = b2f(av.x); As[lk + 1][lm] = b2f(av.y);
      As[lk + 2][lm] = b2f(av.z); As[lk + 3][lm] = b2f(av.w);
    }
    const size_t wi = (size_t)(kt + bk) * N + col0 + bn;
    if (in_f32) {
      float4 wv = *(const float4*)((const float*)W + wi);
      Bs[bk][bn + 0] = wv.x; Bs[bk][bn + 1] = wv.y;
      Bs[bk][bn + 2] = wv.z; Bs[bk][bn + 3] = wv.w;
    } else {
      ushort4 wv = *(const ushort4*)((const ushortT*)W + wi);
      Bs[bk][bn + 0] = b2f(wv.x); Bs[bk][bn + 1] = b2f(wv.y);
      Bs[bk][bn + 2] = b2f(wv.z); Bs[bk][bn + 3] = b2f(wv.w);
    }
    __syncthreads();
    #pragma unroll
    for (int k = 0; k < 16; k++) {
      float4 a = *(const float4*)&As[k][m0];
      float4 b = *(const float4*)&Bs[k][n0];
      acc[0][0] += a.x*b.x; acc[0][1] += a.x*b.y; acc[0][2] += a.x*b.z; acc[0][3] += a.x*b.w;
      acc[1][0] += a.y*b.x; acc[1][1] += a.y*b.y; acc[1][2] += a.y*b.z; acc[1][3] += a.y*b.w;
      acc[2][0] += a.z*b.x; acc[2][1] += a.z*b.y; acc[2][2] += a.z*b.z; acc[2][3] += a.z*b.w;
      acc[3][0] += a.w*b.x; acc[3][1] += a.w*b.y; acc[3][2] += a.w*b.z; acc[3][3] += a.w*b.w;
    }
    __syncthreads();
  }

  float bv0 = ldin(bias, col0 + n0 + 0, in_f32);
  float bv1 = ldin(bias, col0 + n0 + 1, in_f32);
  float bv2 = ldin(bias, col0 + n0 + 2, in_f32);
  float bv3 = ldin(bias, col0 + n0 + 3, in_f32);
  #pragma unroll
  for (int i = 0; i < 4; i++) {
    float v0 = acc[i][0] + bv0;
    float v1 = acc[i][1] + bv1;
    float v2 = acc[i][2] + bv2;
    float v3 = acc[i][3] + bv3;
    if (relu) { v0 = fmaxf(v0, 0.f); v1 = fmaxf(v1, 0.f); v2 = fmaxf(v2, 0.f); v3 = fmaxf(v3, 0.f); }
    ushort4 o;
    o.x = f2b(v0); o.y = f2b(v1); o.z = f2b(v2); o.w = f2b(v3);
    *(ushort4*)&out[(size_t)(row0 + m0 + i) * N + col0 + n0] = o;
  }
}

// ---------------------------------------------------------------------------
// Fused add + LayerNorm. X: input or bf16 intermediate (x_dyn); Y: bf16.
// Store: bf16 unless (store_dyn && input dtype is f32).
// ---------------------------------------------------------------------------
__global__ __launch_bounds__(256) void add_ln_kernel(
    const void* __restrict__ X, const ushortT* __restrict__ Y,
    const void* __restrict__ gamma, const void* __restrict__ beta,
    void* __restrict__ out, const ushortT* __restrict__ sniffp,
    int x_dyn, int store_dyn)
{
  const int row = blockIdx.x;
  const int tid = threadIdx.x;
  const int in_f32 = sniff_is_f32(sniffp);
  const int xf32 = x_dyn ? in_f32 : 0;
  const size_t base = (size_t)row * D_;
  float v = ldin(X, base + tid, xf32) + b2f(Y[base + tid]);
  float s = v, q = v * v;
  #pragma unroll
  for (int off = 32; off > 0; off >>= 1) {
    s += __shfl_xor(s, off, 64);
    q += __shfl_xor(q, off, 64);
  }
  __shared__ float rs[4], rq[4];
  if ((tid & 63) == 0) { rs[tid >> 6] = s; rq[tid >> 6] = q; }
  __syncthreads();
  float S = rs[0] + rs[1] + rs[2] + rs[3];
  float Q = rq[0] + rq[1] + rq[2] + rq[3];
  float mu = S * (1.f / D_);
  float var = Q * (1.f / D_) - mu * mu;
  float rstd = rsqrtf(var + 1e-6f);
  float r = ldin(gamma, tid, in_f32) * (v - mu) * rstd + ldin(beta, tid, in_f32);
  if (store_dyn && in_f32) ((float*)out)[base + tid] = r;
  else                     ((ushortT*)out)[base + tid] = f2b(r);
}

// ---------------------------------------------------------------------------
// Dual attention. Q/K/V are bf16 intermediates; ADJ/M1/M2 are inputs (dual).
// ---------------------------------------------------------------------------
__global__ __launch_bounds__(256) void attn_kernel(
    const ushortT* __restrict__ Q,  const ushortT* __restrict__ K1,
    const ushortT* __restrict__ V1, const ushortT* __restrict__ K2,
    const ushortT* __restrict__ V2, const void* __restrict__ ADJ,
    const void* __restrict__ M1, const void* __restrict__ M2,
    ushortT* __restrict__ OUT, const ushortT* __restrict__ sniffp)
{
  const float scale = 0.17677669529663687f;  // 1/sqrt(32)
  const int b = blockIdx.y;
  const int q0 = blockIdx.x * 4;
  const int tid = threadIdx.x;
  const int in_f32 = sniff_is_f32(sniffp);

  __shared__ float qs[4][256];
  __shared__ float sc[4][8][258];

  #pragma unroll
  for (int qq = 0; qq < 4; qq++)
    qs[qq][tid] = b2f(Q[((size_t)b * N1_ + q0 + qq) * D_ + tid]);
  __syncthreads();

  const int h = tid >> 5, l = tid & 31;
  float cacc[4] = {0.f, 0.f, 0.f, 0.f};

  for (int src = 0; src < 2; src++) {
    const ushortT* Kp = src ? K2 : K1;
    const ushortT* Vp = src ? V2 : V1;

    {
      const int t = tid;
      float valid[4];
      if (src == 0) {
        float m1v = ldin(M1, (size_t)b * N1_ + t, in_f32);
        #pragma unroll
        for (int qq = 0; qq < 4; qq++) {
          float av = ldin(ADJ, ((size_t)b * N1_ + q0 + qq) * N1_ + t, in_f32);
          valid[qq] = (av * m1v) > 0.f ? 1.f : 0.f;
        }
      } else {
        float m2v = ldin(M2, (size_t)b * N2_ + t, in_f32);
        #pragma unroll
        for (int qq = 0; qq < 4; qq++) valid[qq] = (m2v > 0.f) ? 1.f : 0.f;
      }
      const ushortT* kr = &Kp[((size_t)b * 256 + t) * D_];
      for (int hh = 0; hh < 8; hh++) {
        float kv[32];
        const uint4* kp = (const uint4*)(kr + hh * 32);
        #pragma unroll
        for (int c4 = 0; c4 < 4; c4++) {
          uint4 u = kp[c4];
          kv[c4*8+0] = __uint_as_float(u.x << 16);
          kv[c4*8+1] = __uint_as_float(u.x & 0xffff0000u);
          kv[c4*8+2] = __uint_as_float(u.y << 16);
          kv[c4*8+3] = __uint_as_float(u.y & 0xffff0000u);
          kv[c4*8+4] = __uint_as_float(u.z << 16);
          kv[c4*8+5] = __uint_as_float(u.z & 0xffff0000u);
          kv[c4*8+6] = __uint_as_float(u.w << 16);
          kv[c4*8+7] = __uint_as_float(u.w & 0xffff0000u);
        }
        float s0 = 0.f, s1 = 0.f, s2 = 0.f, s3 = 0.f;
        #pragma unroll
        for (int j = 0; j < 32; j++) {
          float kk = kv[j];
          s0 += qs[0][hh*32+j] * kk;
          s1 += qs[1][hh*32+j] * kk;
          s2 += qs[2][hh*32+j] * kk;
          s3 += qs[3][hh*32+j] * kk;
        }
        sc[0][hh][t] = valid[0] ? s0 * scale : -1e9f;
        sc[1][hh][t] = valid[1] ? s1 * scale : -1e9f;
        sc[2][hh][t] = valid[2] ? s2 * scale : -1e9f;
        sc[3][hh][t] = valid[3] ? s3 * scale : -1e9f;
      }
    }
    __syncthreads();

    for (int qq = 0; qq < 4; qq++) {
      float mx = -1e30f;
      for (int i = l; i < 256; i += 32) mx = fmaxf(mx, sc[qq][h][i]);
      #pragma unroll
      for (int off = 16; off > 0; off >>= 1) mx = fmaxf(mx, __shfl_xor(mx, off, 32));
      float sum = 0.f;
      for (int i = l; i < 256; i += 32) {
        float e = __expf(sc[qq][h][i] - mx);
        sc[qq][h][i] = e;
        sum += e;
      }
      #pragma unroll
      for (int off = 16; off > 0; off >>= 1) sum += __shfl_xor(sum, off, 32);
      float inv = 1.f / sum;
      for (int i = l; i < 256; i += 32) sc[qq][h][i] *= inv;
    }
    __syncthreads();

    #pragma unroll 4
    for (int t = 0; t < 256; t++) {
      float w = b2f(Vp[((size_t)b * 256 + t) * D_ + tid]);
      #pragma unroll
      for (int qq = 0; qq < 4; qq++) cacc[qq] += sc[qq][h][t] * w;
    }
    __syncthreads();
  }

  #pragma unroll
  for (int qq = 0; qq < 4; qq++)
    OUT[((size_t)b * N1_ + q0 + qq) * D_ + tid] = f2b(cacc[qq]);
}

// ---------------------------------------------------------------------------
// Orchestration. SZ = 32768*256 bf16 elements (16 MB).
// Layout A (ws >= 96MB): q,k1,v1,k2,v2,out1 in ws; ffn1 overlays k1..v2;
//   ffn2 overlays q; final LN -> d_out (never scratch; f32-safe).
// Layout B (ws >= 80MB): q..v2 in ws; out1 in d_out (bf16); ffn1 overlays
//   k1..v2; ffn2 overlays q; final LN in-place on d_out (bf16-safe).
// ---------------------------------------------------------------------------
extern "C" void kernel_launch(void* const* d_in, const int* in_sizes, int n_in,
                              void* d_out, int out_size, void* d_ws, size_t ws_size,
                              hipStream_t stream) {
  const void* x1    = d_in[0];
  const void* adj1  = d_in[1];
  const void* mask1 = d_in[2];
  const void* x2    = d_in[3];
  const void* mask2 = d_in[4];
  const void* Wq = d_in[5];  const void* bq = d_in[6];
  const void* Wk = d_in[7];  const void* bk = d_in[8];
  const void* Wv = d_in[9];  const void* bv = d_in[10];
  const void* Wo = d_in[11]; const void* bo = d_in[12];
  const void* W1 = d_in[13]; const void* b1 = d_in[14];
  const void* W2 = d_in[15]; const void* b2 = d_in[16];
  const void* g1 = d_in[17]; const void* be1= d_in[18];
  const void* g2 = d_in[19]; const void* be2= d_in[20];
  const ushortT* sniffp = (const ushortT*)x1;

  ushortT* ws = (ushortT*)d_ws;
  const size_t SZ = (size_t)M_ * D_;
  const bool big = ws_size >= (size_t)(6 * SZ * 2);

  ushortT* qb    = ws;
  ushortT* k1b   = ws + SZ;
  ushortT* v1b   = ws + 2*SZ;
  ushortT* k2b   = ws + 3*SZ;
  ushortT* v2b   = ws + 4*SZ;
  ushortT* out1b = big ? (ws + 5*SZ) : (ushortT*)d_out;
  ushortT* ffn1b = ws + SZ;   // overlays k1..v2 (32768*1024 elems)
  ushortT* ffn2b = ws;        // overlays q/c
  ushortT* attnp = k1b;       // attn-proj result overlays k1

  dim3 blk(256);
  dim3 gProj(M_/64, D_/64);      // 512 x 4
  dim3 gFfn1(M_/64, DFF_/64);    // 512 x 16

  // QKV projections (A = input x1/x2 -> a_dyn=1)
  gemm_bias_kernel<<<gProj, blk, 0, stream>>>(x1, Wq, bq, qb,  M_, D_, D_, 0, sniffp, 1);
  gemm_bias_kernel<<<gProj, blk, 0, stream>>>(x1, Wk, bk, k1b, M_, D_, D_, 0, sniffp, 1);
  gemm_bias_kernel<<<gProj, blk, 0, stream>>>(x1, Wv, bv, v1b, M_, D_, D_, 0, sniffp, 1);
  gemm_bias_kernel<<<gProj, blk, 0, stream>>>(x2, Wk, bk, k2b, M_, D_, D_, 0, sniffp, 1);
  gemm_bias_kernel<<<gProj, blk, 0, stream>>>(x2, Wv, bv, v2b, M_, D_, D_, 0, sniffp, 1);

  // Dual attention -> c1+c2 (in place over q)
  attn_kernel<<<dim3(N1_/4, B_), blk, 0, stream>>>(qb, k1b, v1b, k2b, v2b,
                                                   adj1, mask1, mask2, qb, sniffp);

  // Output projection (A = bf16 intermediate), residual + LN (X = input x1)
  gemm_bias_kernel<<<gProj, blk, 0, stream>>>(qb, Wo, bo, attnp, M_, D_, D_, 0, sniffp, 0);
  add_ln_kernel<<<dim3(M_), blk, 0, stream>>>(x1, attnp, g1, be1, out1b, sniffp, 1, 0);

  // FFN (A operands are bf16 intermediates)
  gemm_bias_kernel<<<gFfn1, blk, 0, stream>>>(out1b, W1, b1, ffn1b, M_, DFF_, D_, 1, sniffp, 0);
  gemm_bias_kernel<<<gProj, blk, 0, stream>>>(ffn1b, W2, b2, ffn2b, M_, D_, DFF_, 0, sniffp, 0);

  // Final residual + LN -> d_out (store dtype follows input dtype)
  add_ln_kernel<<<dim3(M_), blk, 0, stream>>>(out1b, ffn2b, g2, be2, d_out, sniffp, 0, 1);
}

// Round 4
// 1428.748 us; speedup vs baseline: 1.3392x; 1.3392x over previous
//
#include <hip/hip_runtime.h>
#include <hip/hip_bf16.h>
#include <stdint.h>

// Problem constants (PrismEncoder)
#define B_   128
#define N1_  256
#define N2_  256
#define D_   256
#define H_   8
#define DH_  32
#define DFF_ 1024
#define M_   (B_*N1_)   // 32768 rows

typedef unsigned short ushortT;
typedef unsigned int   uintT;
typedef short bf16x8 __attribute__((ext_vector_type(8)));
typedef float f32x4  __attribute__((ext_vector_type(4)));

__device__ __forceinline__ float b2f(ushortT u){ return __uint_as_float(((uintT)u)<<16); }
__device__ __forceinline__ ushortT f2b(float f){
  uintT u = __float_as_uint(f);
  uintT r = (u + 0x7fffu + ((u>>16)&1u)) >> 16;   // RNE
  return (ushortT)r;
}

// Dtype sniff: bf16 N(0,1) exponents cluster in [100,135]; f32 halves don't.
// (Evidence says inputs are f32; keep the sniff anyway — it is cheap and safe.)
__device__ __forceinline__ int sniff_is_f32(const ushortT* x){
  int bad = 0;
  #pragma unroll
  for (int i = 0; i < 64; i++) {
    int e = (x[i] >> 7) & 0xff;
    bad += (e < 100 || e > 135) ? 1 : 0;
  }
  return bad >= 12;
}
__device__ __forceinline__ float ldin(const void* p, size_t i, int f32){
  return f32 ? ((const float*)p)[i] : b2f(((const ushortT*)p)[i]);
}

// ---------------------------------------------------------------------------
// Convert input tensor (sniffed dtype) -> bf16. 8 elems/thread.
// ---------------------------------------------------------------------------
__global__ __launch_bounds__(256) void conv_bf16_kernel(
    const void* __restrict__ X, ushortT* __restrict__ Y, int n8,
    const ushortT* __restrict__ sniffp)
{
  const int in_f32 = sniff_is_f32(sniffp);
  int i = blockIdx.x * 256 + threadIdx.x;
  if (i >= n8) return;
  size_t base = (size_t)i * 8;
  if (in_f32) {
    float4 a = *(const float4*)((const float*)X + base);
    float4 b = *(const float4*)((const float*)X + base + 4);
    ushort4 o0, o1;
    o0.x=f2b(a.x); o0.y=f2b(a.y); o0.z=f2b(a.z); o0.w=f2b(a.w);
    o1.x=f2b(b.x); o1.y=f2b(b.y); o1.z=f2b(b.z); o1.w=f2b(b.w);
    *(ushort4*)(Y + base)     = o0;
    *(ushort4*)(Y + base + 4) = o1;
  } else {
    *(uint4*)(Y + base) = *(const uint4*)((const ushortT*)X + base);
  }
}

// ---------------------------------------------------------------------------
// Transpose W[K,N] (sniffed dtype) -> Wt[N,K] bf16. 32x32 tiles.
// ---------------------------------------------------------------------------
__global__ __launch_bounds__(256) void transpose_w_kernel(
    const void* __restrict__ W, ushortT* __restrict__ Wt, int K, int N,
    const ushortT* __restrict__ sniffp)
{
  const int in_f32 = sniff_is_f32(sniffp);
  __shared__ float t[32][33];
  const int tx = threadIdx.x & 31, ty = threadIdx.x >> 5;  // ty 0..7
  const int n0 = blockIdx.x * 32, k0 = blockIdx.y * 32;
  #pragma unroll
  for (int i = 0; i < 4; i++)
    t[ty + 8*i][tx] = ldin(W, (size_t)(k0 + ty + 8*i) * N + n0 + tx, in_f32);
  __syncthreads();
  #pragma unroll
  for (int i = 0; i < 4; i++)
    Wt[(size_t)(n0 + ty + 8*i) * K + k0 + tx] = f2b(t[tx][ty + 8*i]);
}

// ---------------------------------------------------------------------------
// MFMA GEMM: C[M,N] = A[M,K](bf16) @ B + bias, opt relu, optional fused
// residual+LayerNorm epilogue (requires N==256, gridDim.y==1).
// b_mode 0: B given as Bt[N,K] bf16 (pre-transposed).
// b_mode 1: B given as B[K,N] in sniffed input dtype; transposed during
//           LDS staging (thread = column, 4x uint4 LDS writes per chunk).
// Block 256 thr = 4 waves. Tile 64 rows x 256 cols; wave w -> cols [64w,64w+64).
// BK=32, LDS stride 40 elems (16B-aligned rows).
// Verified MFMA mappings (guide §3): A[m=lane&15][k=(lane>>4)*8+j],
// B[n=lane&15][k=(lane>>4)*8+j] from B^T rows, C/D col=lane&15,
// row=(lane>>4)*4+reg.
// ---------------------------------------------------------------------------
__global__ __launch_bounds__(256) void gemm_bt_kernel(
    const ushortT* __restrict__ A, const void* __restrict__ Bsrc,
    const void* __restrict__ bias, ushortT* __restrict__ C,
    int M, int N, int K, int relu, int b_mode,
    int fuse_ln, const ushortT* __restrict__ residual,
    const void* __restrict__ gamma, const void* __restrict__ beta,
    void* __restrict__ outp, int store_dyn,
    const ushortT* __restrict__ sniffp)
{
  __shared__ ushortT Al[64 * 40];
  __shared__ ushortT Bl[256 * 40];
  __shared__ float rsum[4][64], rsq[4][64], mus[64], rstds[64];

  const int tid = threadIdx.x;
  const int in_f32 = sniff_is_f32(sniffp);
  const int wave = tid >> 6, lane = tid & 63;
  const int l15 = lane & 15, l4 = lane >> 4;
  const int row0 = blockIdx.x * 64;
  const int col0 = blockIdx.y * 256;

  f32x4 acc[4][4];
  #pragma unroll
  for (int i = 0; i < 4; i++)
    #pragma unroll
    for (int j = 0; j < 4; j++) acc[i][j] = (f32x4)0.f;

  const int sr = tid >> 2;          // staging row (A: 0..63)
  const int sk = (tid & 3) * 8;     // staging k-offset (elems)

  for (int kt = 0; kt < K; kt += 32) {
    // stage A tile [64][32]
    uint4 av = *(const uint4*)&A[(size_t)(row0 + sr) * K + kt + sk];
    *(uint4*)&Al[sr * 40 + sk] = av;
    if (b_mode == 0) {
      // stage Bt tile [256 n][32 k], 4 rounds
      #pragma unroll
      for (int rr = 0; rr < 4; rr++) {
        int r = sr + rr * 64;
        uint4 bv = *(const uint4*)&((const ushortT*)Bsrc)[(size_t)(col0 + r) * K + kt + sk];
        *(uint4*)&Bl[r * 40 + sk] = bv;
      }
    } else {
      // stage B[K,N] chunk [32 k][256 n] transposed: thread = column
      const int c = tid;
      #pragma unroll
      for (int g = 0; g < 4; g++) {
        ushortT tmp[8];
        if (in_f32) {
          #pragma unroll
          for (int i = 0; i < 8; i++)
            tmp[i] = f2b(((const float*)Bsrc)[(size_t)(kt + g*8 + i) * N + col0 + c]);
        } else {
          #pragma unroll
          for (int i = 0; i < 8; i++)
            tmp[i] = ((const ushortT*)Bsrc)[(size_t)(kt + g*8 + i) * N + col0 + c];
        }
        *(uint4*)&Bl[c * 40 + g * 8] = *(uint4*)tmp;
      }
    }
    __syncthreads();
    bf16x8 af[4], bf[4];
    #pragma unroll
    for (int mt = 0; mt < 4; mt++)
      af[mt] = *(const bf16x8*)&Al[(mt * 16 + l15) * 40 + l4 * 8];
    #pragma unroll
    for (int nt = 0; nt < 4; nt++)
      bf[nt] = *(const bf16x8*)&Bl[(wave * 64 + nt * 16 + l15) * 40 + l4 * 8];
    #pragma unroll
    for (int mt = 0; mt < 4; mt++)
      #pragma unroll
      for (int nt = 0; nt < 4; nt++)
        acc[mt][nt] = __builtin_amdgcn_mfma_f32_16x16x32_bf16(af[mt], bf[nt], acc[mt][nt], 0, 0, 0);
    __syncthreads();
  }

  if (!fuse_ln) {
    #pragma unroll
    for (int nt = 0; nt < 4; nt++) {
      int col = col0 + wave * 64 + nt * 16 + l15;
      float bb = ldin(bias, col, in_f32);
      #pragma unroll
      for (int mt = 0; mt < 4; mt++) {
        #pragma unroll
        for (int r = 0; r < 4; r++) {
          float v = acc[mt][nt][r] + bb;
          if (relu) v = fmaxf(v, 0.f);
          int row = row0 + mt * 16 + l4 * 4 + r;
          C[(size_t)row * N + col] = f2b(v);
        }
      }
    }
    return;
  }

  // ---- fused residual + LayerNorm epilogue (N==256, col0==0) ----
  // residual is ALWAYS a separate bf16 buffer (never aliases outp) -> no race.
  #pragma unroll
  for (int nt = 0; nt < 4; nt++) {
    int col = wave * 64 + nt * 16 + l15;
    float bb = ldin(bias, col, in_f32);
    #pragma unroll
    for (int mt = 0; mt < 4; mt++) {
      #pragma unroll
      for (int r = 0; r < 4; r++) {
        int row = mt * 16 + l4 * 4 + r;
        float res = b2f(residual[(size_t)(row0 + row) * 256 + col]);
        acc[mt][nt][r] += bb + res;
      }
    }
  }
  #pragma unroll
  for (int mt = 0; mt < 4; mt++) {
    #pragma unroll
    for (int r = 0; r < 4; r++) {
      float s = 0.f, q = 0.f;
      #pragma unroll
      for (int nt = 0; nt < 4; nt++) {
        float v = acc[mt][nt][r];
        s += v; q += v * v;
      }
      #pragma unroll
      for (int off = 1; off < 16; off <<= 1) {
        s += __shfl_xor(s, off, 64);
        q += __shfl_xor(q, off, 64);
      }
      if (l15 == 0) {
        int row = mt * 16 + l4 * 4 + r;
        rsum[wave][row] = s;
        rsq[wave][row]  = q;
      }
    }
  }
  __syncthreads();
  if (tid < 64) {
    float S = rsum[0][tid] + rsum[1][tid] + rsum[2][tid] + rsum[3][tid];
    float Q = rsq[0][tid]  + rsq[1][tid]  + rsq[2][tid]  + rsq[3][tid];
    float mu = S * (1.f / 256.f);
    float var = Q * (1.f / 256.f) - mu * mu;
    mus[tid] = mu;
    rstds[tid] = rsqrtf(var + 1e-6f);
  }
  __syncthreads();
  #pragma unroll
  for (int nt = 0; nt < 4; nt++) {
    int col = wave * 64 + nt * 16 + l15;
    float g  = ldin(gamma, col, in_f32);
    float be = ldin(beta,  col, in_f32);
    #pragma unroll
    for (int mt = 0; mt < 4; mt++) {
      #pragma unroll
      for (int r = 0; r < 4; r++) {
        int row = mt * 16 + l4 * 4 + r;
        float o = g * (acc[mt][nt][r] - mus[row]) * rstds[row] + be;
        size_t idx = (size_t)(row0 + row) * 256 + col;
        if (store_dyn && in_f32) ((float*)outp)[idx] = o;
        else                     ((ushortT*)outp)[idx] = f2b(o);
      }
    }
  }
}

// ---------------------------------------------------------------------------
// Fused add + LayerNorm (LN1). X: input (dual); Y: bf16; out bf16.
// ---------------------------------------------------------------------------
__global__ __launch_bounds__(256) void add_ln_kernel(
    const void* __restrict__ X, const ushortT* __restrict__ Y,
    const void* __restrict__ gamma, const void* __restrict__ beta,
    ushortT* __restrict__ out, const ushortT* __restrict__ sniffp)
{
  const int row = blockIdx.x;
  const int tid = threadIdx.x;
  const int in_f32 = sniff_is_f32(sniffp);
  const size_t base = (size_t)row * D_;
  float v = ldin(X, base + tid, in_f32) + b2f(Y[base + tid]);
  float s = v, q = v * v;
  #pragma unroll
  for (int off = 32; off > 0; off >>= 1) {
    s += __shfl_xor(s, off, 64);
    q += __shfl_xor(q, off, 64);
  }
  __shared__ float rs[4], rq[4];
  if ((tid & 63) == 0) { rs[tid >> 6] = s; rq[tid >> 6] = q; }
  __syncthreads();
  float S = rs[0] + rs[1] + rs[2] + rs[3];
  float Q = rq[0] + rq[1] + rq[2] + rq[3];
  float mu = S * (1.f / D_);
  float var = Q * (1.f / D_) - mu * mu;
  float rstd = rsqrtf(var + 1e-6f);
  out[base + tid] = f2b(ldin(gamma, tid, in_f32) * (v - mu) * rstd + ldin(beta, tid, in_f32));
}

// ---------------------------------------------------------------------------
// Dual attention, 4 queries/block, vectorized LDS traffic.
// ---------------------------------------------------------------------------
__global__ __launch_bounds__(256) void attn_kernel(
    const ushortT* __restrict__ Q,  const ushortT* __restrict__ K1,
    const ushortT* __restrict__ V1, const ushortT* __restrict__ K2,
    const ushortT* __restrict__ V2, const void* __restrict__ ADJ,
    const void* __restrict__ M1, const void* __restrict__ M2,
    ushortT* __restrict__ OUT, const ushortT* __restrict__ sniffp)
{
  const float scale = 0.17677669529663687f;  // 1/sqrt(32)
  const int b = blockIdx.y;
  const int q0 = blockIdx.x * 4;
  const int tid = threadIdx.x;
  const int in_f32 = sniff_is_f32(sniffp);

  __shared__ __align__(16) float qs[4][256];
  __shared__ __align__(16) float sc[4][8][260];

  #pragma unroll
  for (int qq = 0; qq < 4; qq++)
    qs[qq][tid] = b2f(Q[((size_t)b * N1_ + q0 + qq) * D_ + tid]);
  __syncthreads();

  const int h = tid >> 5, l = tid & 31;
  float cacc[4] = {0.f, 0.f, 0.f, 0.f};

  for (int src = 0; src < 2; src++) {
    const ushortT* Kp = src ? K2 : K1;
    const ushortT* Vp = src ? V2 : V1;

    // ---- scores: thread = key t
    {
      const int t = tid;
      float valid[4];
      if (src == 0) {
        float m1v = ldin(M1, (size_t)b * N1_ + t, in_f32);
        #pragma unroll
        for (int qq = 0; qq < 4; qq++) {
          float av = ldin(ADJ, ((size_t)b * N1_ + q0 + qq) * N1_ + t, in_f32);
          valid[qq] = (av * m1v) > 0.f ? 1.f : 0.f;
        }
      } else {
        float m2v = ldin(M2, (size_t)b * N2_ + t, in_f32);
        #pragma unroll
        for (int qq = 0; qq < 4; qq++) valid[qq] = (m2v > 0.f) ? 1.f : 0.f;
      }
      const ushortT* kr = &Kp[((size_t)b * 256 + t) * D_];
      for (int hh = 0; hh < 8; hh++) {
        float4 kv4[8];
        const uint4* kp = (const uint4*)(kr + hh * 32);
        #pragma unroll
        for (int c4 = 0; c4 < 4; c4++) {
          uint4 u = kp[c4];
          kv4[c4*2+0].x = __uint_as_float(u.x << 16);
          kv4[c4*2+0].y = __uint_as_float(u.x & 0xffff0000u);
          kv4[c4*2+0].z = __uint_as_float(u.y << 16);
          kv4[c4*2+0].w = __uint_as_float(u.y & 0xffff0000u);
          kv4[c4*2+1].x = __uint_as_float(u.z << 16);
          kv4[c4*2+1].y = __uint_as_float(u.z & 0xffff0000u);
          kv4[c4*2+1].z = __uint_as_float(u.w << 16);
          kv4[c4*2+1].w = __uint_as_float(u.w & 0xffff0000u);
        }
        float s0 = 0.f, s1 = 0.f, s2 = 0.f, s3 = 0.f;
        #pragma unroll
        for (int j4 = 0; j4 < 8; j4++) {
          float4 k4 = kv4[j4];
          float4 a0 = *(const float4*)&qs[0][hh*32 + j4*4];
          float4 a1 = *(const float4*)&qs[1][hh*32 + j4*4];
          float4 a2 = *(const float4*)&qs[2][hh*32 + j4*4];
          float4 a3 = *(const float4*)&qs[3][hh*32 + j4*4];
          s0 += a0.x*k4.x + a0.y*k4.y + a0.z*k4.z + a0.w*k4.w;
          s1 += a1.x*k4.x + a1.y*k4.y + a1.z*k4.z + a1.w*k4.w;
          s2 += a2.x*k4.x + a2.y*k4.y + a2.z*k4.z + a2.w*k4.w;
          s3 += a3.x*k4.x + a3.y*k4.y + a3.z*k4.z + a3.w*k4.w;
        }
        sc[0][hh][t] = valid[0] ? s0 * scale : -1e9f;
        sc[1][hh][t] = valid[1] ? s1 * scale : -1e9f;
        sc[2][hh][t] = valid[2] ? s2 * scale : -1e9f;
        sc[3][hh][t] = valid[3] ? s3 * scale : -1e9f;
      }
    }
    __syncthreads();

    // ---- softmax: 32-lane group per head
    for (int qq = 0; qq < 4; qq++) {
      float mx = -1e30f;
      for (int i = l; i < 256; i += 32) mx = fmaxf(mx, sc[qq][h][i]);
      #pragma unroll
      for (int off = 16; off > 0; off >>= 1) mx = fmaxf(mx, __shfl_xor(mx, off, 32));
      float sum = 0.f;
      for (int i = l; i < 256; i += 32) {
        float e = __expf(sc[qq][h][i] - mx);
        sc[qq][h][i] = e;
        sum += e;
      }
      #pragma unroll
      for (int off = 16; off > 0; off >>= 1) sum += __shfl_xor(sum, off, 32);
      float inv = 1.f / sum;
      for (int i = l; i < 256; i += 32) sc[qq][h][i] *= inv;
    }
    __syncthreads();

    // ---- accumulate: thread (h, dh)
    for (int t4 = 0; t4 < 64; t4++) {
      int t = t4 * 4;
      float w0 = b2f(Vp[((size_t)b * 256 + t + 0) * D_ + tid]);
      float w1 = b2f(Vp[((size_t)b * 256 + t + 1) * D_ + tid]);
      float w2 = b2f(Vp[((size_t)b * 256 + t + 2) * D_ + tid]);
      float w3 = b2f(Vp[((size_t)b * 256 + t + 3) * D_ + tid]);
      #pragma unroll
      for (int qq = 0; qq < 4; qq++) {
        float4 p = *(const float4*)&sc[qq][h][t];
        cacc[qq] += p.x*w0 + p.y*w1 + p.z*w2 + p.w*w3;
      }
    }
    __syncthreads();
  }

  #pragma unroll
  for (int qq = 0; qq < 4; qq++)
    OUT[((size_t)b * N1_ + q0 + qq) * D_ + tid] = f2b(cacc[qq]);
}

// ---------------------------------------------------------------------------
// Orchestration. SZ = 32768*256 elems; 5 ws slots (80 MiB — known available).
// d_out used as bf16 scratch ONLY before the final write (x1c, v1).
//   conv x2 -> S0; W-pack {Wkt,Wvt,Wqt,Wot} -> S1 front; k2->S3, v2->S4;
//   conv x1 -> d_out; q->S0 (x2c dead); k1->S2; v1->d_out (in-place, row-safe);
//   attn -> c@S0 (in-place over q); attn-proj -> S2 (k1 dead);
//   LN1 -> out1@S0 (c dead); FFN1 (W1 direct, b_mode=1) -> S1..S4 (pack dead);
//   FFN2 (W2 direct, b_mode=1) + residual(S0) + LN2 -> d_out (fresh write,
//   no aliasing with residual in EITHER dtype -> round-3 race eliminated).
// ---------------------------------------------------------------------------
extern "C" void kernel_launch(void* const* d_in, const int* in_sizes, int n_in,
                              void* d_out, int out_size, void* d_ws, size_t ws_size,
                              hipStream_t stream) {
  const void* x1    = d_in[0];
  const void* adj1  = d_in[1];
  const void* mask1 = d_in[2];
  const void* x2    = d_in[3];
  const void* mask2 = d_in[4];
  const void* Wq = d_in[5];  const void* bq = d_in[6];
  const void* Wk = d_in[7];  const void* bk = d_in[8];
  const void* Wv = d_in[9];  const void* bv = d_in[10];
  const void* Wo = d_in[11]; const void* bo = d_in[12];
  const void* W1 = d_in[13]; const void* b1 = d_in[14];
  const void* W2 = d_in[15]; const void* b2 = d_in[16];
  const void* g1 = d_in[17]; const void* be1= d_in[18];
  const void* g2 = d_in[19]; const void* be2= d_in[20];
  const ushortT* sniffp = (const ushortT*)x1;

  ushortT* ws = (ushortT*)d_ws;
  const size_t SZ = (size_t)M_ * D_;
  ushortT* S0 = ws;
  ushortT* S1 = ws + SZ;
  ushortT* S2 = ws + 2*SZ;
  ushortT* S3 = ws + 3*SZ;
  ushortT* S4 = ws + 4*SZ;
  ushortT* dOut = (ushortT*)d_out;

  // Weight-transpose pack at front of S1 (dead before FFN1 overwrites S1)
  ushortT* Wkt = S1;
  ushortT* Wvt = S1 + 65536;
  ushortT* Wqt = S1 + 131072;
  ushortT* Wot = S1 + 196608;

  dim3 blk(256);
  dim3 gGemmD(M_/64, 1);         // N=256 GEMMs
  dim3 gGemmF(M_/64, DFF_/256);  // FFN1, N=1024
  dim3 gT256(8, 8);
  const int n8 = (int)(SZ / 8);

  // 0) convert x2 -> S0 ; transpose Wk,Wv,Wq,Wo -> S1 pack
  conv_bf16_kernel<<<dim3((n8+255)/256), blk, 0, stream>>>(x2, S0, n8, sniffp);
  transpose_w_kernel<<<gT256, blk, 0, stream>>>(Wk, Wkt, D_, D_, sniffp);
  transpose_w_kernel<<<gT256, blk, 0, stream>>>(Wv, Wvt, D_, D_, sniffp);
  transpose_w_kernel<<<gT256, blk, 0, stream>>>(Wq, Wqt, D_, D_, sniffp);
  transpose_w_kernel<<<gT256, blk, 0, stream>>>(Wo, Wot, D_, D_, sniffp);

  // 1) k2 = x2c@Wk + bk -> S3 ; v2 = x2c@Wv + bv -> S4
  gemm_bt_kernel<<<gGemmD, blk, 0, stream>>>(S0, Wkt, bk, S3, M_, D_, D_, 0, 0,
      0, nullptr, nullptr, nullptr, nullptr, 0, sniffp);
  gemm_bt_kernel<<<gGemmD, blk, 0, stream>>>(S0, Wvt, bv, S4, M_, D_, D_, 0, 0,
      0, nullptr, nullptr, nullptr, nullptr, 0, sniffp);

  // 2) convert x1 -> d_out scratch (x2c dead after step 1)
  conv_bf16_kernel<<<dim3((n8+255)/256), blk, 0, stream>>>(x1, dOut, n8, sniffp);

  // 3) q -> S0 ; k1 -> S2 ; v1 -> d_out (in-place over x1c, row-partitioned)
  gemm_bt_kernel<<<gGemmD, blk, 0, stream>>>(dOut, Wqt, bq, S0, M_, D_, D_, 0, 0,
      0, nullptr, nullptr, nullptr, nullptr, 0, sniffp);
  gemm_bt_kernel<<<gGemmD, blk, 0, stream>>>(dOut, Wkt, bk, S2, M_, D_, D_, 0, 0,
      0, nullptr, nullptr, nullptr, nullptr, 0, sniffp);
  gemm_bt_kernel<<<gGemmD, blk, 0, stream>>>(dOut, Wvt, bv, dOut, M_, D_, D_, 0, 0,
      0, nullptr, nullptr, nullptr, nullptr, 0, sniffp);

  // 4) attention: q@S0, k1@S2, v1@dOut, k2@S3, v2@S4 -> c@S0 (in place)
  attn_kernel<<<dim3(N1_/4, B_), blk, 0, stream>>>(S0, S2, dOut, S3, S4,
                                                   adj1, mask1, mask2, S0, sniffp);

  // 5) attn-proj: c@Wo + bo -> S2 (k1 dead)
  gemm_bt_kernel<<<gGemmD, blk, 0, stream>>>(S0, Wot, bo, S2, M_, D_, D_, 0, 0,
      0, nullptr, nullptr, nullptr, nullptr, 0, sniffp);

  // 6) LN1: x1 + attnp@S2 -> out1@S0 (c dead)
  add_ln_kernel<<<dim3(M_), blk, 0, stream>>>(x1, S2, g1, be1, S0, sniffp);

  // 7) FFN1: relu(out1@S0 @ W1 + b1) -> S1..S4 (b_mode=1: W1 read directly)
  gemm_bt_kernel<<<gGemmF, blk, 0, stream>>>(S0, W1, b1, S1, M_, DFF_, D_, 1, 1,
      0, nullptr, nullptr, nullptr, nullptr, 0, sniffp);

  // 8) FFN2 + residual(S0) + LN2 fused -> d_out (b_mode=1; fresh write)
  gemm_bt_kernel<<<gGemmD, blk, 0, stream>>>(S1, W2, b2, nullptr, M_, D_, DFF_, 0, 1,
      1, S0, g2, be2, d_out, 1, sniffp);
}